// Round 1
// 96.023 us; speedup vs baseline: 1.0605x; 1.0605x over previous
//
#include <hip/hip_runtime.h>
#include <stdint.h>

// Problem constants (from reference setup_inputs)
#define BATCH 4096
#define ISZ   512
#define OSZ   512
#define KDIM  4096           // contraction dim: k = i*8 + d

// GEMM tiling
#define TM 128
#define TN 128
#define BK 64
#define SPLITK 4

typedef __bf16 bf16x8 __attribute__((ext_vector_type(8)));
typedef float  f32x4  __attribute__((ext_vector_type(4)));

__device__ __forceinline__ unsigned short f2bf(float f) {
    uint32_t u = __float_as_uint(f);
    u = (u + 0x7FFFu + ((u >> 16) & 1u)) >> 16;
    return (unsigned short)u;
}

// R7: merged prep kernel.
//  blocks [0, 2048):    coef fp32 [O][I][D] -> bf16 [O][K]   (k-contiguous)
//  blocks [2048, 10240): jacobi8(tanh(x)) -> A bf16 [BATCH][KDIM]
// Both memory-bound; merging overlaps them in one dispatch. Exact-size
// grids, no bounds checks. Jacobi is computed ONCE here (was recomputed
// 4x inside the GEMM, once per n-block — that in-loop VALU/TRANS was the
// GEMM bottleneck theory for R7).
#define NB_CONV 2048         // (OSZ*KDIM/4) / 256
#define NB_JAC  8192         // (BATCH*ISZ)  / 256
__global__ __launch_bounds__(256) void prep(
    const float* __restrict__ coef, unsigned short* __restrict__ coefb,
    const float* __restrict__ X,    unsigned short* __restrict__ Ab)
{
    const int b = blockIdx.x;
    if (b < NB_CONV) {
        int idx = b * 256 + threadIdx.x;
        float4 v = reinterpret_cast<const float4*>(coef)[idx];
        uint2 o;
        o.x = (uint32_t)f2bf(v.x) | ((uint32_t)f2bf(v.y) << 16);
        o.y = (uint32_t)f2bf(v.z) | ((uint32_t)f2bf(v.w) << 16);
        reinterpret_cast<uint2*>(coefb)[idx] = o;
    } else {
        int idx = (b - NB_CONV) * 256 + threadIdx.x;   // over [BATCH][ISZ]
        float x = X[idx];
        // tanh(x) = 1 - 2/(exp(2x)+1); err ~1e-6 << bf16 ulp
        float e  = __expf(2.0f * x);
        float t  = 1.0f - 2.0f * __builtin_amdgcn_rcpf(e + 1.0f);
        float p0 = 1.0f;
        float p1 = 2.0f * t;
        float p2 = (1.875f     * t) * p1 - 0.75f       * p0;
        float p3 = (1.8666667f * t) * p2 - 0.8f        * p1;
        float p4 = (1.875f     * t) * p3 - 0.83333333f * p2;
        float p5 = (1.8857143f * t) * p4 - 0.85714287f * p3;
        float p6 = (1.8958333f * t) * p5 - 0.875f      * p4;
        float p7 = (1.9047619f * t) * p6 - 0.88888889f * p5;
        uint4 o;
        o.x = (uint32_t)f2bf(p0) | ((uint32_t)f2bf(p1) << 16);
        o.y = (uint32_t)f2bf(p2) | ((uint32_t)f2bf(p3) << 16);
        o.z = (uint32_t)f2bf(p4) | ((uint32_t)f2bf(p5) << 16);
        o.w = (uint32_t)f2bf(p6) | ((uint32_t)f2bf(p7) << 16);
        reinterpret_cast<uint4*>(Ab)[idx] = o;       // A[b][i*8 + d] = p_d
    }
}

// Pure bf16 GEMM, split-K partials with plain stores.
// Structure history: R3 atomics = ~50us TCC serialization (removed);
// R5 in-register A = 2x duplicated VALU (reverted); R6 = shared-A-via-LDS
// jacobi fusion; R7 = jacobi hoisted to prep (it throttled MFMA: ~230
// VALU + 8 TRANS insts/thread/iter at 2 waves/SIMD, duplicated per
// n-block). Both A and B now stage via global_load_lds (16B chunks),
// double-buffered, prefetch-distance-1: next tile's async loads fly
// through this tile's MFMA phase; barrier drains vmcnt only.
// 128x128 block tile, BK=64, 256 threads = 4 waves (2x2), wave tile 64x64
// via 4x4 of mfma_f32_16x16x32_bf16 (layout verified R1-R5).
// LDS XOR swizzle: slot = row*8 + (c ^ (row&7)); global_load_lds keeps
// its wave-uniform-base + lane*16 dest contract (swizzle applied on the
// per-lane SOURCE address). SQ_LDS_BANK_CONFLICT == 0 measured R2-R5.
__global__ __launch_bounds__(256, 2) void gemm_fused(
    const unsigned short* __restrict__ Am,  // [BATCH][KDIM] bf16 bits
    const unsigned short* __restrict__ Bm,  // [OSZ][KDIM] bf16 bits
    unsigned short* __restrict__ Cp,        // [SPLITK][M][N] bf16 partials
    int M, int N, int K)
{
    __shared__ __align__(16) unsigned short As[2][TM * BK];   // 2 x 16 KB
    __shared__ __align__(16) unsigned short Bs[2][TN * BK];   // 2 x 16 KB

    const int tid  = threadIdx.x;
    const int wave = tid >> 6;
    const int lane = tid & 63;
    const int wm   = (wave >> 1) * 64;      // wave row offset in tile
    const int wn   = (wave & 1) * 64;       // wave col offset in tile

    const size_t baseA = (size_t)blockIdx.x * TM * K;
    const size_t baseB = (size_t)blockIdx.y * TN * K;
    const int kper  = K / SPLITK;           // 1024
    const int kbeg  = blockIdx.z * kper;
    const int niter = kper / BK;            // 16

    f32x4 acc[4][4] = {};

    const int mrow = lane & 15;             // m within 16x16 tile
    const int kc   = lane >> 4;             // 16B-chunk column offset within k

    // Staging: 128x64 bf16 = 16 KB = 1024 chunks of 16B; 256 thr x 4 its.
    // Dest chunk s is linear (wave-uniform base + lane*16); source col is
    // pre-swizzled so LDS chunk (row, sc) holds global col sc ^ (row&7).
    auto stage = [&](const unsigned short* __restrict__ G, size_t gbase,
                     unsigned short* lds, int k0) {
        #pragma unroll
        for (int it = 0; it < 4; ++it) {
            int s    = it * 256 + tid;
            int row  = s >> 3;
            int csrc = (s & 7) ^ (row & 7);
            const unsigned short* g = G + gbase + (size_t)row * K + k0 + csrc * 8;
            unsigned short* l = lds + (size_t)(it * 256 + wave * 64) * 8;
            __builtin_amdgcn_global_load_lds(
                (const __attribute__((address_space(1))) uint32_t*)g,
                (__attribute__((address_space(3))) uint32_t*)l, 16, 0, 0);
        }
    };

    stage(Bm, baseB, &Bs[0][0], kbeg);
    stage(Am, baseA, &As[0][0], kbeg);
    __syncthreads();

    for (int kt = 0; kt < niter; ++kt) {
        const int k0 = kbeg + kt * BK;
        const int p  = kt & 1;
        if (kt + 1 < niter) {
            stage(Bm, baseB, &Bs[1 - p][0], k0 + BK);  // async, flies through
            stage(Am, baseA, &As[1 - p][0], k0 + BK);  // the MFMA phase
        }

        const unsigned short* Ap = &As[p][0];
        const unsigned short* Bp = &Bs[p][0];
        #pragma unroll
        for (int ks = 0; ks < BK; ks += 32) {
            bf16x8 aF[4], bF[4];
            const int cbase = (ks >> 3) + kc;
            #pragma unroll
            for (int mi = 0; mi < 4; ++mi) {
                int r = wm + mi * 16 + mrow;
                int slot = r * 8 + (cbase ^ (r & 7));
                aF[mi] = *reinterpret_cast<const bf16x8*>(Ap + (size_t)slot * 8);
            }
            #pragma unroll
            for (int ni = 0; ni < 4; ++ni) {
                int r = wn + ni * 16 + mrow;
                int slot = r * 8 + (cbase ^ (r & 7));
                bF[ni] = *reinterpret_cast<const bf16x8*>(Bp + (size_t)slot * 8);
            }
            #pragma unroll
            for (int mi = 0; mi < 4; ++mi)
                #pragma unroll
                for (int ni = 0; ni < 4; ++ni)
                    acc[mi][ni] = __builtin_amdgcn_mfma_f32_16x16x32_bf16(
                        aF[mi], bF[ni], acc[mi][ni], 0, 0, 0);
        }
        __syncthreads();   // completes buf[1-p] stage; fences buf[p] reuse
    }

    // bf16 partials, plain stores (no atomics).
    // C/D layout (m89-verified): col = lane&15, row = (lane>>4)*4 + r
    unsigned short* Cz = Cp + (size_t)blockIdx.z * M * N;
    const int orow = blockIdx.x * TM + wm + (lane >> 4) * 4;
    const int ocol = blockIdx.y * TN + wn + (lane & 15);
    #pragma unroll
    for (int mi = 0; mi < 4; ++mi)
        #pragma unroll
        for (int ni = 0; ni < 4; ++ni)
            #pragma unroll
            for (int r = 0; r < 4; ++r)
                Cz[(size_t)(orow + mi * 16 + r) * N + ocol + ni * 16] =
                    f2bf(acc[mi][ni][r]);
}

// out = sum over SPLITK bf16 partials (fp32 accumulate), 8 outputs/thread
// (R7: widened to 16B/lane loads)
__global__ __launch_bounds__(256) void reduce_k(
    const unsigned short* __restrict__ part, float* __restrict__ out, int n8)
{
    int idx = blockIdx.x * 256 + threadIdx.x;
    if (idx >= n8) return;
    const uint4* p = reinterpret_cast<const uint4*>(part);   // 8 bf16 / uint4
    float s[8] = {};
    #pragma unroll
    for (int z = 0; z < SPLITK; ++z) {
        uint4 v = p[(size_t)z * n8 + idx];
        s[0] += __uint_as_float((v.x & 0xFFFFu) << 16);
        s[1] += __uint_as_float(v.x & 0xFFFF0000u);
        s[2] += __uint_as_float((v.y & 0xFFFFu) << 16);
        s[3] += __uint_as_float(v.y & 0xFFFF0000u);
        s[4] += __uint_as_float((v.z & 0xFFFFu) << 16);
        s[5] += __uint_as_float(v.z & 0xFFFF0000u);
        s[6] += __uint_as_float((v.w & 0xFFFFu) << 16);
        s[7] += __uint_as_float(v.w & 0xFFFF0000u);
    }
    float4 o0 = {s[0], s[1], s[2], s[3]};
    float4 o1 = {s[4], s[5], s[6], s[7]};
    reinterpret_cast<float4*>(out)[2 * idx]     = o0;
    reinterpret_cast<float4*>(out)[2 * idx + 1] = o1;
}

extern "C" void kernel_launch(void* const* d_in, const int* in_sizes, int n_in,
                              void* d_out, int out_size, void* d_ws, size_t ws_size,
                              hipStream_t stream)
{
    const float* x    = (const float*)d_in[0];   // [4096][512]
    const float* coef = (const float*)d_in[1];   // [512][512][8]
    float* out = (float*)d_out;                  // [4096][512]

    // workspace: bf16 partials [SPLITK][4096][512] (16.8 MB)
    //          + coef bf16 [512][4096]             (4.2 MB)
    //          + A bf16 [4096][4096]               (33.5 MB)
    unsigned short* part  = (unsigned short*)d_ws;
    unsigned short* coefb = part  + (size_t)SPLITK * BATCH * OSZ;
    unsigned short* Ab    = coefb + (size_t)OSZ * KDIM;

    prep<<<NB_CONV + NB_JAC, 256, 0, stream>>>(coef, coefb, x, Ab);

    dim3 grid(BATCH / TM, OSZ / TN, SPLITK);     // 32 x 4 x 4 = 512 blocks
    gemm_fused<<<grid, 256, 0, stream>>>(Ab, coefb, part, BATCH, OSZ, KDIM);

    int n8r = (BATCH * OSZ) / 8;                 // 262,144
    reduce_k<<<(n8r + 255) / 256, 256, 0, stream>>>(part, out, n8r);
}